// Round 9
// baseline (353.274 us; speedup 1.0000x reference)
//
#include <hip/hip_runtime.h>
#include <stdint.h>

#define DIM 1280
#define HEADS 16
#define HD 80
#define TOTAL 8192
#define CHUNK 1024
#define QKVN 3840

typedef __attribute__((ext_vector_type(8))) __bf16 bf16x8;
typedef __attribute__((ext_vector_type(4))) float floatx4;

typedef __attribute__((address_space(1))) const uint32_t gu32;
typedef __attribute__((address_space(3))) uint32_t lu32;

__device__ __forceinline__ void llds16(const void* g, void* l) {
  __builtin_amdgcn_global_load_lds((gu32*)g, (lu32*)l, 16, 0, 0);
}

__device__ __forceinline__ unsigned short f2b(float f) {
  union { __bf16 b; unsigned short u; } x; x.b = (__bf16)f; return x.u;
}
__device__ __forceinline__ float b2f(unsigned short u) {
  union { __bf16 b; unsigned short u; } x; x.u = u; return (float)x.b;
}
__device__ __forceinline__ float fexp2(float x) {
#if __has_builtin(__builtin_amdgcn_exp2f)
  return __builtin_amdgcn_exp2f(x);
#else
  return __expf(x * 0.6931471805599453f);
#endif
}

// scale(80^-0.5) * log2(e), folded into Q on load
#define QSCALE (0.11180339887498949f * 1.44269504088896340f)

// image geometry
#define KT_SH (64 * 104)        // k tile: 64 keys x (80 + 24 pad) shorts = 13312 B
#define VT_SH (80 * 72)         // v tile: 80 d-rows x (64 keys + 8 pad) shorts = 11520 B

// ---------------- fp32 -> bf16 convert ----------------
__global__ void cvt_bf16(const float* __restrict__ src, unsigned short* __restrict__ dst, int n4) {
  int i = blockIdx.x * 256 + threadIdx.x;
  if (i >= n4) return;
  float4 v = reinterpret_cast<const float4*>(src)[i];
  ushort4 o;
  o.x = f2b(v.x); o.y = f2b(v.y); o.z = f2b(v.z); o.w = f2b(v.w);
  reinterpret_cast<ushort4*>(dst)[i] = o;
}

// ================= 256x256 single-barrier-per-phase GEMM (round-3 verified) =================
// Round-9: XCD-aware block swizzle (grid%8==0 for both launches): consecutive
// blocks on one XCD share the B panel -> L2 reuse.  K-loop unchanged.
// Round-4 lesson: MFMA-first region order.  Round-6/7/8: V epilogue via
// per-wave LDS transpose (full 128B-contiguous stores into vimg).

// stage A half: rows [0,64)+[128,192) (hi=0) or +64 (hi=64); 2 loads/thread
__device__ __forceinline__ void stage_a64(const unsigned short* __restrict__ G,
                                          unsigned short* ls, int wv, int lane,
                                          int row0, int kk, int hi) {
#pragma unroll
  for (int t = 0; t < 2; ++t) {
    const int stripe = t * 8 + wv;
    const int rb = ((stripe >> 3) << 7) + ((stripe & 7) << 3) + hi;
    const int r = rb + (lane >> 3);
    const int ch = (lane & 7) ^ (r & 7);
    llds16(G + (size_t)(row0 + r) * DIM + kk + (ch << 3), ls + rb * 64);
  }
}

// stage B half: rows wc*64+[0,32) for all wc (hi=0) or +32 (hi=32)
__device__ __forceinline__ void stage_b64(const unsigned short* __restrict__ G,
                                          unsigned short* ls, int wv, int lane,
                                          int row0, int kk, int hi) {
#pragma unroll
  for (int t = 0; t < 2; ++t) {
    const int stripe = t * 8 + wv;
    const int rb = ((stripe >> 2) << 6) + ((stripe & 3) << 3) + hi;
    const int r = rb + (lane >> 3);
    const int ch = (lane & 7) ^ (r & 7);
    llds16(G + (size_t)(row0 + r) * DIM + kk + (ch << 3), ls + rb * 64);
  }
}

__device__ __forceinline__ bf16x8 frg(const unsigned short* ls, int r, int cx) {
  return *reinterpret_cast<const bf16x8*>(ls + r * 64 + (cx << 3));
}

#define MFMA_BF16 __builtin_amdgcn_mfma_f32_16x16x32_bf16
#define LGKM0() asm volatile("s_waitcnt lgkmcnt(0)" ::: "memory")
#define BARR()  asm volatile("s_barrier" ::: "memory")

template<int MODE>
__launch_bounds__(512, 2)
__global__ void gemm8(const unsigned short* __restrict__ A,
                      const unsigned short* __restrict__ B,
                      const float* __restrict__ bias,
                      unsigned short* __restrict__ qo,
                      unsigned short* __restrict__ ko,
                      unsigned short* __restrict__ vo,
                      float* __restrict__ fo) {
  __shared__ __attribute__((aligned(16))) unsigned short lsA[2][256 * 64];  // 64 KiB
  __shared__ __attribute__((aligned(16))) unsigned short lsB[2][256 * 64];  // 64 KiB
  // XCD-aware swizzle: nbk % 8 == 0 for both launches (480, 160).
  const int nbk = gridDim.x * gridDim.y;
  const int bid = blockIdx.y * gridDim.x + blockIdx.x;
  const int nb = (bid & 7) * (nbk >> 3) + (bid >> 3);
  const int bxm = nb % gridDim.x;
  const int by = nb / gridDim.x;
  const int m0 = bxm * 256;
  const int n0 = by * 256;
  const int tid = threadIdx.x;
  const int wv = tid >> 6, lane = tid & 63;
  const int wr = wv >> 2, wc = wv & 3;
  const int q4 = lane >> 4, l15 = lane & 15;
  const int sx = l15 & 7;
  const int cx0 = q4 ^ sx;          // swizzled chunk slot, k-chunk q4
  const int cx1 = (4 + q4) ^ sx;    // swizzled chunk slot, k-chunk 4+q4

  // ---- prologue: 7 stages (tile 0 complete + 3/4 of tile 1) ----
  stage_a64(A, &lsA[0][0], wv, lane, m0, 0, 0);    // A-lo(0)
  stage_b64(B, &lsB[0][0], wv, lane, n0, 0, 0);    // B-lo(0)
  stage_b64(B, &lsB[0][0], wv, lane, n0, 0, 32);   // B-hi(0)
  stage_a64(A, &lsA[0][0], wv, lane, m0, 0, 64);   // A-hi(0)
  stage_b64(B, &lsB[1][0], wv, lane, n0, 64, 0);   // B-lo(1)
  stage_a64(A, &lsA[1][0], wv, lane, m0, 64, 0);   // A-lo(1)
  stage_b64(B, &lsB[1][0], wv, lane, n0, 64, 32);  // B-hi(1)

  floatx4 acc[8][4];
#pragma unroll
  for (int i = 0; i < 8; ++i)
#pragma unroll
    for (int j = 0; j < 4; ++j)
      acc[i][j] = (floatx4){0.f, 0.f, 0.f, 0.f};

  asm volatile("s_waitcnt vmcnt(6)" ::: "memory");   // tile 0 fully landed
  BARR();

  const int rA = wr * 128 + l15;
  const int rB = wc * 64 + l15;

  bf16x8 ArLo[4][2], ArHi[4][2], Blo[2][2], Bhi[2][2];

#pragma unroll 2
  for (int kt = 0; kt < 20; ++kt) {
    const unsigned short* la = &lsA[kt & 1][0];
    const unsigned short* lb = &lsB[kt & 1][0];
    unsigned short* aN = &lsA[(kt & 1) ^ 1][0];   // next buf (tile kt+1)
    unsigned short* aC = &lsA[kt & 1][0];         // current buf (tile kt+2)
    unsigned short* bC = &lsB[kt & 1][0];
    const bool st1 = (kt + 1 < 20);
    const bool st2 = (kt + 2 < 20);

    // ---- R0: MFMA Q3(kt-1) [ArHi x Blo, regs] | read A-lo,B-lo | stage A-hi(kt+1) ----
    if (kt > 0) {
#pragma unroll
      for (int m = 0; m < 4; ++m)
#pragma unroll
        for (int n = 0; n < 2; ++n) {
          acc[m + 4][n] = MFMA_BF16(ArHi[m][0], Blo[n][0], acc[m + 4][n], 0, 0, 0);
          acc[m + 4][n] = MFMA_BF16(ArHi[m][1], Blo[n][1], acc[m + 4][n], 0, 0, 0);
        }
    }
#pragma unroll
    for (int m = 0; m < 4; ++m) {
      ArLo[m][0] = frg(la, rA + m * 16, cx0);
      ArLo[m][1] = frg(la, rA + m * 16, cx1);
    }
#pragma unroll
    for (int n = 0; n < 2; ++n) {
      Blo[n][0] = frg(lb, rB + n * 16, cx0);
      Blo[n][1] = frg(lb, rB + n * 16, cx1);
    }
    if (st1) stage_a64(A, aN, wv, lane, m0, (kt + 1) * 64, 64);   // A-hi(kt+1)
    LGKM0();
    BARR();

    // ---- R1: MFMA Q0 [ArLo x Blo] | read B-hi | stage B-lo(kt+2) ----
#pragma unroll
    for (int m = 0; m < 4; ++m)
#pragma unroll
      for (int n = 0; n < 2; ++n) {
        acc[m][n] = MFMA_BF16(ArLo[m][0], Blo[n][0], acc[m][n], 0, 0, 0);
        acc[m][n] = MFMA_BF16(ArLo[m][1], Blo[n][1], acc[m][n], 0, 0, 0);
      }
#pragma unroll
    for (int n = 0; n < 2; ++n) {
      Bhi[n][0] = frg(lb, rB + (n + 2) * 16, cx0);
      Bhi[n][1] = frg(lb, rB + (n + 2) * 16, cx1);
    }
    if (st2) stage_b64(B, bC, wv, lane, n0, (kt + 2) * 64, 0);    // B-lo(kt+2)
    LGKM0();
    BARR();

    // ---- R2: MFMA Q1 [ArLo x Bhi] | read A-hi | stage A-lo(kt+2) ----
#pragma unroll
    for (int m = 0; m < 4; ++m)
#pragma unroll
      for (int n = 0; n < 2; ++n) {
        acc[m][n + 2] = MFMA_BF16(ArLo[m][0], Bhi[n][0], acc[m][n + 2], 0, 0, 0);
        acc[m][n + 2] = MFMA_BF16(ArLo[m][1], Bhi[n][1], acc[m][n + 2], 0, 0, 0);
      }
#pragma unroll
    for (int m = 0; m < 4; ++m) {
      ArHi[m][0] = frg(la, rA + (m + 4) * 16, cx0);
      ArHi[m][1] = frg(la, rA + (m + 4) * 16, cx1);
    }
    if (st2) stage_a64(A, aC, wv, lane, m0, (kt + 2) * 64, 0);    // A-lo(kt+2)
    LGKM0();
    BARR();

    // ---- R3: MFMA Q2 [ArHi x Bhi] | stage B-hi(kt+2) | vmcnt | BARR ----
#pragma unroll
    for (int m = 0; m < 4; ++m)
#pragma unroll
      for (int n = 0; n < 2; ++n) {
        acc[m + 4][n + 2] = MFMA_BF16(ArHi[m][0], Bhi[n][0], acc[m + 4][n + 2], 0, 0, 0);
        acc[m + 4][n + 2] = MFMA_BF16(ArHi[m][1], Bhi[n][1], acc[m + 4][n + 2], 0, 0, 0);
      }
    if (st2) stage_b64(B, bC, wv, lane, n0, (kt + 2) * 64, 32);   // B-hi(kt+2)
    if (st2)      asm volatile("s_waitcnt vmcnt(6)" ::: "memory");  // tile kt+1 ready
    else if (st1) asm volatile("s_waitcnt vmcnt(0)" ::: "memory");  // drain for last tile
    BARR();
  }

  // peeled final quadrant: Q3(19) from registers
#pragma unroll
  for (int m = 0; m < 4; ++m)
#pragma unroll
    for (int n = 0; n < 2; ++n) {
      acc[m + 4][n] = MFMA_BF16(ArHi[m][0], Blo[n][0], acc[m + 4][n], 0, 0, 0);
      acc[m + 4][n] = MFMA_BF16(ArHi[m][1], Blo[n][1], acc[m + 4][n], 0, 0, 0);
    }

  // ---------------- epilogue ----------------
  if (MODE == 0) {
    if (by >= 10) {
      // V region -> transposed vimg via per-wave LDS transpose (coalesced).
      unsigned short* scr = (wv < 4) ? (&lsA[0][0] + wv * 8192)
                                     : (&lsB[0][0] + (wv - 4) * 8192);
      const int base_c = n0 - 2 * DIM + wc * 64;
      // write phase: acc -> scratch [cloc(64)][rloc(128)], XOR-swizzled rows
#pragma unroll
      for (int n = 0; n < 4; ++n) {
        const int cloc = n * 16 + l15;
        const float bn = bias[2 * DIM + base_c + cloc];
        const int swz = (cloc & 7) << 4;
#pragma unroll
        for (int m = 0; m < 8; ++m) {
          const int rloc = m * 16 + q4 * 4;
          ushort4 w;
          w.x = f2b(acc[m][n][0] + bn);
          w.y = f2b(acc[m][n][1] + bn);
          w.z = f2b(acc[m][n][2] + bn);
          w.w = f2b(acc[m][n][3] + bn);
          *reinterpret_cast<ushort4*>(scr + cloc * 128 + (rloc ^ swz)) = w;
        }
      }
      // read phase: 16-lane groups store full 128B d-row runs
#pragma unroll
      for (int jtc = 0; jtc < 2; ++jtc) {
        const int rowg = m0 + wr * 128 + jtc * 64;
        const int chn = rowg >> 10, jtn = (rowg >> 6) & 15;
#pragma unroll
        for (int cb = 0; cb < 16; ++cb) {
          const int col = cb * 4 + q4;
          const int c = base_c + col;
          const int h = c / 80;
          const int d = c - h * 80;
          const int rloc = jtc * 64 + l15 * 4;
          const ushort4 w = *reinterpret_cast<const ushort4*>(
              scr + col * 128 + (rloc ^ ((col & 7) << 4)));
          *reinterpret_cast<ushort4*>(
              vo + (size_t)((chn * 16 + h) * 16 + jtn) * VT_SH + d * 72 + l15 * 4) = w;
        }
      }
      return;
    }
    unsigned short* os;
    int nloc = n0;
    if (by < 5) { os = qo; }
    else        { os = ko; nloc = n0 - DIM; }
#pragma unroll
    for (int n = 0; n < 4; ++n) {
      const int cg = wc * 64 + n * 16 + l15;
      const float bn = bias[n0 + cg];
#pragma unroll
      for (int m = 0; m < 8; ++m) {
#pragma unroll
        for (int r = 0; r < 4; ++r) {
          const int row = m0 + wr * 128 + m * 16 + q4 * 4 + r;
          os[(size_t)row * DIM + nloc + cg] = f2b(acc[m][n][r] + bn);
        }
      }
    }
    return;
  }
  // MODE 1: fp32 output
#pragma unroll
  for (int n = 0; n < 4; ++n) {
    const int cg = wc * 64 + n * 16 + l15;
    const float bn = bias[n0 + cg];
#pragma unroll
    for (int m = 0; m < 8; ++m) {
#pragma unroll
      for (int r = 0; r < 4; ++r) {
        const int row = m0 + wr * 128 + m * 16 + q4 * 4 + r;
        fo[(size_t)row * DIM + n0 + cg] = acc[m][n][r] + bn;
      }
    }
  }
}

// ---------------- prepass: RoPE K -> K image (vectorized; Q is roped in attn) ----------------
// One block per global row m: threads 0..159 rope (h=t/10, d0=4*(t%10));
// threads 160..255 write the 24-short pads (96 = 16 heads x 6 ushort4).
__global__ void prep_k(const unsigned short* __restrict__ kbuf,
                       const float* __restrict__ cp, const float* __restrict__ sp,
                       unsigned short* __restrict__ kimg) {
  const int m = blockIdx.x, tid = threadIdx.x;
  const int ch = m >> 10, rl = m & 1023;
  const int jt = rl >> 6, rr = rl & 63;

  if (tid < 160) {
    const int h = tid / 10, j = tid - h * 10;
    const int d0 = 4 * j;
    const float4 c4 = *reinterpret_cast<const float4*>(cp + (size_t)m * HD + d0);
    const float4 s4 = *reinterpret_cast<const float4*>(sp + (size_t)m * HD + d0);
    const ushort4 lo = *reinterpret_cast<const ushort4*>(kbuf + (size_t)m * DIM + h * HD + d0);
    const ushort4 hi = *reinterpret_cast<const ushort4*>(kbuf + (size_t)m * DIM + h * HD + d0 + 40);
    ushort4 o1, o2;
    o1.x = f2b(b2f(lo.x) * c4.x - b2f(hi.x) * s4.x);
    o1.y = f2b(b2f(lo.y) * c4.y - b2f(hi.y) * s4.y);
    o1.z = f2b(b2f(lo.z) * c4.z - b2f(hi.z) * s4.z);
    o1.w = f2b(b2f(lo.w) * c4.w - b2f(hi.w) * s4.w);
    o2.x = f2b(b2f(hi.x) * c4.x + b2f(lo.x) * s4.x);
    o2.y = f2b(b2f(hi.y) * c4.y + b2f(lo.y) * s4.y);
    o2.z = f2b(b2f(hi.z) * c4.z + b2f(lo.z) * s4.z);
    o2.w = f2b(b2f(hi.w) * c4.w + b2f(lo.w) * s4.w);
    const size_t ob = ((size_t)((ch * 16 + h) * 16 + jt) * KT_SH) + rr * 104;
    *reinterpret_cast<ushort4*>(kimg + ob + d0) = o1;
    *reinterpret_cast<ushort4*>(kimg + ob + d0 + 40) = o2;
  } else {
    const int t = tid - 160;            // 0..95: 16 heads x 6 ushort4 pads
    const int h = t / 6, qi = t - h * 6;
    const size_t ob = ((size_t)((ch * 16 + h) * 16 + jt) * KT_SH) + rr * 104;
    *reinterpret_cast<ushort4*>(kimg + ob + 80 + 4 * qi) = (ushort4){0, 0, 0, 0};
  }
}

// ---------------- flash attention v3 (dbuf K/V staging; RoPE-Q on load) ----------------
// Round-9: (a) Q fragments built from row-major qbuf with RoPE+QSCALE applied
// in registers (partner d+/-40 is an aligned 8-elem run in the same row;
// d0>=80 fragments are the old zero-pad).  (b) XCD grouping: the 8 qt-blocks
// of one (ch,h) — which read the SAME K/V images — are placed stride-8 on one
// XCD (temporally adjacent -> L2-served instead of 8x L3 fetches).
__launch_bounds__(256, 2)
__global__ void attn_k(const unsigned short* __restrict__ qbuf,
                       const unsigned short* __restrict__ kimg,
                       const unsigned short* __restrict__ vimg,
                       const float* __restrict__ cp, const float* __restrict__ sp,
                       unsigned short* __restrict__ ob) {
  __shared__ __attribute__((aligned(16))) unsigned short lsK[2][KT_SH];   // 2 x 13312 B
  __shared__ __attribute__((aligned(16))) unsigned short lsV[2][VT_SH];   // 2 x 11520 B
  __shared__ __attribute__((aligned(16))) unsigned short lsP[128 * 72];   // 18432 B

  // XCD grouping: i=(gh*64)+(q*8)+x -> group g=gh*8+x on XCD x, member q.
  const int i = blockIdx.x;
  const int x = i & 7, t_ = i >> 3;
  const int qt = t_ & 7;
  const int g = (t_ >> 3) * 8 + x;     // 0..127
  const int h = g & 15, ch = g >> 4;
  const int tid = threadIdx.x, wv = tid >> 6, lane = tid & 63;
  const int q4 = lane >> 4, l15 = lane & 15;
  const int qrow_loc = qt * 128 + wv * 32;

  // Q fragments: RoPE + QSCALE applied on load from row-major qbuf
  bf16x8 aq[2][3];
#pragma unroll
  for (int mt = 0; mt < 2; ++mt) {
    const int m_row = ch * 1024 + qrow_loc + mt * 16 + l15;
    const unsigned short* qr = qbuf + (size_t)m_row * DIM + h * HD;
    const float* cr = cp + (size_t)m_row * HD;
    const float* sr = sp + (size_t)m_row * HD;
#pragma unroll
    for (int ks = 0; ks < 3; ++ks) {
      const int d0 = ks * 32 + q4 * 8;
      union { ushort4 u4[2]; bf16x8 v; } out;
      if (d0 < 80) {
        const bool hi = (d0 >= 40);
        const int pd = hi ? d0 - 40 : d0 + 40;
        const float sg = hi ? 1.0f : -1.0f;
        const ushort4 xa = *reinterpret_cast<const ushort4*>(qr + d0);
        const ushort4 xc = *reinterpret_cast<const ushort4*>(qr + d0 + 4);
        const ushort4 pa = *reinterpret_cast<const ushort4*>(qr + pd);
        const ushort4 pc = *reinterpret_cast<const ushort4*>(qr + pd + 4);
        const float4 c0 = *reinterpret_cast<const float4*>(cr + d0);
        const float4 c1 = *reinterpret_cast<const float4*>(cr + d0 + 4);
        const float4 s0 = *reinterpret_cast<const float4*>(sr + d0);
        const float4 s1 = *reinterpret_cast<const float4*>(sr + d0 + 4);
        ushort4 o0, o1;
        o0.x = f2b((b2f(xa.x) * c0.x + sg * b2f(pa.x) * s0.x) * QSCALE);
        o0.y = f2b((b2f(xa.y) * c0.y + sg * b2f(pa.y) * s0.y) * QSCALE);
        o0.z = f2b((b2f(xa.z) * c0.z + sg * b2f(pa.z) * s0.z) * QSCALE);
        o0.w = f2b((b2f(xa.w) * c0.w + sg * b2f(pa.w) * s0.w) * QSCALE);
        o1.x = f2b((b2f(xc.x) * c1.x + sg * b2f(pc.x) * s1.x) * QSCALE);
        o1.y = f2b((b2f(xc.y) * c1.y + sg * b2f(pc.y) * s1.y) * QSCALE);
        o1.z = f2b((b2f(xc.z) * c1.z + sg * b2f(pc.z) * s1.z) * QSCALE);
        o1.w = f2b((b2f(xc.w) * c1.w + sg * b2f(pc.w) * s1.w) * QSCALE);
        out.u4[0] = o0; out.u4[1] = o1;
      } else {
        out.u4[0] = (ushort4){0, 0, 0, 0};
        out.u4[1] = (ushort4){0, 0, 0, 0};
      }
      aq[mt][ks] = out.v;
    }
  }

  floatx4 oacc[2][5];
  float lpart[2] = {0.f, 0.f};
#pragma unroll
  for (int mt = 0; mt < 2; ++mt)
#pragma unroll
    for (int t = 0; t < 5; ++t) oacc[mt][t] = (floatx4){0.f, 0.f, 0.f, 0.f};

  const char* kbase = (const char*)(kimg + (size_t)(ch * 16 + h) * 16 * KT_SH);
  const char* vbase = (const char*)(vimg + (size_t)(ch * 16 + h) * 16 * VT_SH);

  auto stage_kv = [&](int jt, char* lk, char* lv) {
    const char* kg = kbase + (size_t)jt * (KT_SH * 2);
#pragma unroll
    for (int r = 0; r < 4; ++r) {
      const int off = (r * 4 + wv) * 1024;
      if (off < KT_SH * 2)
        llds16(kg + off + lane * 16, lk + off);
    }
    const char* vg = vbase + (size_t)jt * (VT_SH * 2);
#pragma unroll
    for (int r = 0; r < 3; ++r) {
      const int off = (r * 4 + wv) * 1024;
      if (off < VT_SH * 2) {
        if (off + 1024 <= VT_SH * 2) llds16(vg + off + lane * 16, lv + off);
        else if (lane < 16)          llds16(vg + off + lane * 16, lv + off);
      }
    }
  };

  stage_kv(0, (char*)lsK[0], (char*)lsV[0]);

  for (int jt = 0; jt < 16; ++jt) {
    const int cur = jt & 1;
    __syncthreads();   // implicit vmcnt(0): stage(jt) landed for all waves
    if (jt + 1 < 16)
      stage_kv(jt + 1, (char*)lsK[cur ^ 1], (char*)lsV[cur ^ 1]);

    const unsigned short* lk = lsK[cur];
    const unsigned short* lv = lsV[cur];

    // S^T = K Q^T : rows = keys, cols = q-rows
    floatx4 sfr[2][4];
    __builtin_amdgcn_s_setprio(1);
#pragma unroll
    for (int c = 0; c < 4; ++c) {
      const bf16x8 ak0 = *reinterpret_cast<const bf16x8*>(&lk[(c * 16 + l15) * 104 + 0  + q4 * 8]);
      const bf16x8 ak1 = *reinterpret_cast<const bf16x8*>(&lk[(c * 16 + l15) * 104 + 32 + q4 * 8]);
      const bf16x8 ak2 = *reinterpret_cast<const bf16x8*>(&lk[(c * 16 + l15) * 104 + 64 + q4 * 8]);
#pragma unroll
      for (int mt = 0; mt < 2; ++mt) {
        floatx4 s = (floatx4){0.f, 0.f, 0.f, 0.f};
        s = __builtin_amdgcn_mfma_f32_16x16x32_bf16(ak0, aq[mt][0], s, 0, 0, 0);
        s = __builtin_amdgcn_mfma_f32_16x16x32_bf16(ak1, aq[mt][1], s, 0, 0, 0);
        s = __builtin_amdgcn_mfma_f32_16x16x32_bf16(ak2, aq[mt][2], s, 0, 0, 0);
        sfr[mt][c] = s;
      }
    }
    __builtin_amdgcn_s_setprio(0);

    // softmax numerator: p = 2^s ; packed P writes (4 consecutive keys per thread)
#pragma unroll
    for (int mt = 0; mt < 2; ++mt)
#pragma unroll
      for (int c = 0; c < 4; ++c) {
        const float p0 = fexp2(sfr[mt][c][0]);
        const float p1 = fexp2(sfr[mt][c][1]);
        const float p2 = fexp2(sfr[mt][c][2]);
        const float p3 = fexp2(sfr[mt][c][3]);
        lpart[mt] += (p0 + p1) + (p2 + p3);
        ushort4 w;
        w.x = f2b(p0); w.y = f2b(p1); w.z = f2b(p2); w.w = f2b(p3);
        *reinterpret_cast<ushort4*>(&lsP[(wv * 32 + mt * 16 + l15) * 72 + c * 16 + q4 * 4]) = w;
      }

    // O += P V   (wave-local lsP region; in-wave DS ordering covers RAW)
    __builtin_amdgcn_s_setprio(1);
#pragma unroll
    for (int ks = 0; ks < 2; ++ks) {
      const bf16x8 ap0 = *reinterpret_cast<const bf16x8*>(&lsP[(wv * 32 + 0  + l15) * 72 + ks * 32 + q4 * 8]);
      const bf16x8 ap1 = *reinterpret_cast<const bf16x8*>(&lsP[(wv * 32 + 16 + l15) * 72 + ks * 32 + q4 * 8]);
#pragma unroll
      for (int t = 0; t < 5; ++t) {
        const bf16x8 bv = *reinterpret_cast<const bf16x8*>(&lv[(t * 16 + l15) * 72 + ks * 32 + q4 * 8]);
        oacc[0][t] = __builtin_amdgcn_mfma_f32_16x16x32_bf16(ap0, bv, oacc[0][t], 0, 0, 0);
        oacc[1][t] = __builtin_amdgcn_mfma_f32_16x16x32_bf16(ap1, bv, oacc[1][t], 0, 0, 0);
      }
    }
    __builtin_amdgcn_s_setprio(0);
  }

  // l per q-row (l15) summed over this thread's keys; reduce across q4 groups
#pragma unroll
  for (int mt = 0; mt < 2; ++mt) {
    lpart[mt] += __shfl_xor(lpart[mt], 16, 64);
    lpart[mt] += __shfl_xor(lpart[mt], 32, 64);
  }
  float inv[2];
  inv[0] = 1.0f / lpart[0];
  inv[1] = 1.0f / lpart[1];

  float invr[2][4];
#pragma unroll
  for (int mt = 0; mt < 2; ++mt)
#pragma unroll
    for (int r = 0; r < 4; ++r)
      invr[mt][r] = __shfl(inv[mt], q4 * 4 + r, 64);

#pragma unroll
  for (int mt = 0; mt < 2; ++mt)
#pragma unroll
    for (int t = 0; t < 5; ++t)
#pragma unroll
      for (int r = 0; r < 4; ++r) {
        const int gr = ch * CHUNK + qrow_loc + mt * 16 + q4 * 4 + r;
        const int gc = h * HD + t * 16 + l15;
        ob[(size_t)gr * DIM + gc] = f2b(oacc[mt][t][r] * invr[mt][r]);
      }
}

extern "C" void kernel_launch(void* const* d_in, const int* in_sizes, int n_in,
                              void* d_out, int out_size, void* d_ws, size_t ws_size,
                              hipStream_t stream) {
  (void)in_sizes; (void)n_in; (void)out_size; (void)ws_size;
  const float* hs    = (const float*)d_in[0];
  const float* cosp  = (const float*)d_in[1];
  const float* sinp  = (const float*)d_in[2];
  const float* qkvw  = (const float*)d_in[3];
  const float* qkvb  = (const float*)d_in[4];
  const float* projw = (const float*)d_in[5];
  const float* projb = (const float*)d_in[6];

  char* ws = (char*)d_ws;
  // fresh regions (total footprint 126,877,696 B)
  unsigned short* xb   = (unsigned short*)(ws + 0);            // 20,971,520
  unsigned short* wq   = (unsigned short*)(ws + 20971520);     //  9,830,400
  unsigned short* qbuf = (unsigned short*)(ws + 30801920);     // 20,971,520 (live through attn_k!)
  unsigned short* kbuf = (unsigned short*)(ws + 51773440);     // 20,971,520
  unsigned short* vimg = (unsigned short*)(ws + 72744960);     // 23,592,960 (written by gemm8<0>)
  unsigned short* wp   = (unsigned short*)(ws + 96337920);     //  3,276,800
  unsigned short* kimg = (unsigned short*)(ws + 99614720);     // 27,262,976 -> end 126,877,696
  // aliased regions (stream-serialized reuse of dead buffers)
  unsigned short* obuf = xb;   // over xb (dead after gemm8<0>); NOT qbuf (attn reads it)

  cvt_bf16<<<TOTAL * DIM / 4 / 256, 256, 0, stream>>>(hs, xb, TOTAL * DIM / 4);
  cvt_bf16<<<QKVN * DIM / 4 / 256, 256, 0, stream>>>(qkvw, wq, QKVN * DIM / 4);
  cvt_bf16<<<DIM * DIM / 4 / 256, 256, 0, stream>>>(projw, wp, DIM * DIM / 4);

  gemm8<0><<<dim3(TOTAL / 256, QKVN / 256), 512, 0, stream>>>(
      xb, wq, qkvb, qbuf, kbuf, vimg, nullptr);

  prep_k<<<TOTAL, 256, 0, stream>>>(kbuf, cosp, sinp, kimg);

  attn_k<<<1024, 256, 0, stream>>>(qbuf, kimg, vimg, cosp, sinp, obuf);

  gemm8<1><<<dim3(TOTAL / 256, DIM / 256), 512, 0, stream>>>(
      obuf, wp, projb, nullptr, nullptr, nullptr, (float*)d_out);
}

// Round 10
// 334.759 us; speedup vs baseline: 1.0553x; 1.0553x over previous
//
#include <hip/hip_runtime.h>
#include <stdint.h>

#define DIM 1280
#define HEADS 16
#define HD 80
#define TOTAL 8192
#define CHUNK 1024
#define QKVN 3840

typedef __attribute__((ext_vector_type(8))) __bf16 bf16x8;
typedef __attribute__((ext_vector_type(4))) float floatx4;

typedef __attribute__((address_space(1))) const uint32_t gu32;
typedef __attribute__((address_space(3))) uint32_t lu32;

__device__ __forceinline__ void llds16(const void* g, void* l) {
  __builtin_amdgcn_global_load_lds((gu32*)g, (lu32*)l, 16, 0, 0);
}

__device__ __forceinline__ unsigned short f2b(float f) {
  union { __bf16 b; unsigned short u; } x; x.b = (__bf16)f; return x.u;
}
__device__ __forceinline__ float b2f(unsigned short u) {
  union { __bf16 b; unsigned short u; } x; x.u = u; return (float)x.b;
}
__device__ __forceinline__ float fexp2(float x) {
#if __has_builtin(__builtin_amdgcn_exp2f)
  return __builtin_amdgcn_exp2f(x);
#else
  return __expf(x * 0.6931471805599453f);
#endif
}

// scale(80^-0.5) * log2(e), folded into Q on load
#define QSCALE (0.11180339887498949f * 1.44269504088896340f)

// image geometry
#define KT_SH (64 * 104)        // k tile: 64 keys x (80 + 24 pad) shorts = 13312 B
#define VT_SH (80 * 72)         // v tile: 80 d-rows x (64 keys + 8 pad) shorts = 11520 B

// ---------------- fp32 -> bf16 convert ----------------
__global__ void cvt_bf16(const float* __restrict__ src, unsigned short* __restrict__ dst, int n4) {
  int i = blockIdx.x * 256 + threadIdx.x;
  if (i >= n4) return;
  float4 v = reinterpret_cast<const float4*>(src)[i];
  ushort4 o;
  o.x = f2b(v.x); o.y = f2b(v.y); o.z = f2b(v.z); o.w = f2b(v.w);
  reinterpret_cast<ushort4*>(dst)[i] = o;
}

// ================= 256x256 single-barrier-per-phase GEMM (round-3 verified) =================
// Round-10: XCD swizzle REVERTED (round-9 lesson: remap made each XCD stream
// the whole A matrix -> FETCH 59.7->163.6MB, +9us; default bid order already
// gives 8 temporally-adjacent blocks a shared B panel with L3 serving A).
// Round-4 lesson: MFMA-first region order.  Round-6/7/8: V epilogue via
// per-wave LDS transpose (full 128B-contiguous stores into vimg).

// stage A half: rows [0,64)+[128,192) (hi=0) or +64 (hi=64); 2 loads/thread
__device__ __forceinline__ void stage_a64(const unsigned short* __restrict__ G,
                                          unsigned short* ls, int wv, int lane,
                                          int row0, int kk, int hi) {
#pragma unroll
  for (int t = 0; t < 2; ++t) {
    const int stripe = t * 8 + wv;
    const int rb = ((stripe >> 3) << 7) + ((stripe & 7) << 3) + hi;
    const int r = rb + (lane >> 3);
    const int ch = (lane & 7) ^ (r & 7);
    llds16(G + (size_t)(row0 + r) * DIM + kk + (ch << 3), ls + rb * 64);
  }
}

// stage B half: rows wc*64+[0,32) for all wc (hi=0) or +32 (hi=32)
__device__ __forceinline__ void stage_b64(const unsigned short* __restrict__ G,
                                          unsigned short* ls, int wv, int lane,
                                          int row0, int kk, int hi) {
#pragma unroll
  for (int t = 0; t < 2; ++t) {
    const int stripe = t * 8 + wv;
    const int rb = ((stripe >> 2) << 6) + ((stripe & 3) << 3) + hi;
    const int r = rb + (lane >> 3);
    const int ch = (lane & 7) ^ (r & 7);
    llds16(G + (size_t)(row0 + r) * DIM + kk + (ch << 3), ls + rb * 64);
  }
}

__device__ __forceinline__ bf16x8 frg(const unsigned short* ls, int r, int cx) {
  return *reinterpret_cast<const bf16x8*>(ls + r * 64 + (cx << 3));
}

#define MFMA_BF16 __builtin_amdgcn_mfma_f32_16x16x32_bf16
#define LGKM0() asm volatile("s_waitcnt lgkmcnt(0)" ::: "memory")
#define BARR()  asm volatile("s_barrier" ::: "memory")

template<int MODE>
__launch_bounds__(512, 2)
__global__ void gemm8(const unsigned short* __restrict__ A,
                      const unsigned short* __restrict__ B,
                      const float* __restrict__ bias,
                      unsigned short* __restrict__ qo,
                      unsigned short* __restrict__ ko,
                      unsigned short* __restrict__ vo,
                      float* __restrict__ fo) {
  __shared__ __attribute__((aligned(16))) unsigned short lsA[2][256 * 64];  // 64 KiB
  __shared__ __attribute__((aligned(16))) unsigned short lsB[2][256 * 64];  // 64 KiB
  const int m0 = blockIdx.x * 256;
  const int n0 = blockIdx.y * 256;
  const int tid = threadIdx.x;
  const int wv = tid >> 6, lane = tid & 63;
  const int wr = wv >> 2, wc = wv & 3;
  const int q4 = lane >> 4, l15 = lane & 15;
  const int sx = l15 & 7;
  const int cx0 = q4 ^ sx;          // swizzled chunk slot, k-chunk q4
  const int cx1 = (4 + q4) ^ sx;    // swizzled chunk slot, k-chunk 4+q4

  // ---- prologue: 7 stages (tile 0 complete + 3/4 of tile 1) ----
  stage_a64(A, &lsA[0][0], wv, lane, m0, 0, 0);    // A-lo(0)
  stage_b64(B, &lsB[0][0], wv, lane, n0, 0, 0);    // B-lo(0)
  stage_b64(B, &lsB[0][0], wv, lane, n0, 0, 32);   // B-hi(0)
  stage_a64(A, &lsA[0][0], wv, lane, m0, 0, 64);   // A-hi(0)
  stage_b64(B, &lsB[1][0], wv, lane, n0, 64, 0);   // B-lo(1)
  stage_a64(A, &lsA[1][0], wv, lane, m0, 64, 0);   // A-lo(1)
  stage_b64(B, &lsB[1][0], wv, lane, n0, 64, 32);  // B-hi(1)

  floatx4 acc[8][4];
#pragma unroll
  for (int i = 0; i < 8; ++i)
#pragma unroll
    for (int j = 0; j < 4; ++j)
      acc[i][j] = (floatx4){0.f, 0.f, 0.f, 0.f};

  asm volatile("s_waitcnt vmcnt(6)" ::: "memory");   // tile 0 fully landed
  BARR();

  const int rA = wr * 128 + l15;
  const int rB = wc * 64 + l15;

  bf16x8 ArLo[4][2], ArHi[4][2], Blo[2][2], Bhi[2][2];

#pragma unroll 2
  for (int kt = 0; kt < 20; ++kt) {
    const unsigned short* la = &lsA[kt & 1][0];
    const unsigned short* lb = &lsB[kt & 1][0];
    unsigned short* aN = &lsA[(kt & 1) ^ 1][0];   // next buf (tile kt+1)
    unsigned short* aC = &lsA[kt & 1][0];         // current buf (tile kt+2)
    unsigned short* bC = &lsB[kt & 1][0];
    const bool st1 = (kt + 1 < 20);
    const bool st2 = (kt + 2 < 20);

    // ---- R0: MFMA Q3(kt-1) [ArHi x Blo, regs] | read A-lo,B-lo | stage A-hi(kt+1) ----
    if (kt > 0) {
#pragma unroll
      for (int m = 0; m < 4; ++m)
#pragma unroll
        for (int n = 0; n < 2; ++n) {
          acc[m + 4][n] = MFMA_BF16(ArHi[m][0], Blo[n][0], acc[m + 4][n], 0, 0, 0);
          acc[m + 4][n] = MFMA_BF16(ArHi[m][1], Blo[n][1], acc[m + 4][n], 0, 0, 0);
        }
    }
#pragma unroll
    for (int m = 0; m < 4; ++m) {
      ArLo[m][0] = frg(la, rA + m * 16, cx0);
      ArLo[m][1] = frg(la, rA + m * 16, cx1);
    }
#pragma unroll
    for (int n = 0; n < 2; ++n) {
      Blo[n][0] = frg(lb, rB + n * 16, cx0);
      Blo[n][1] = frg(lb, rB + n * 16, cx1);
    }
    if (st1) stage_a64(A, aN, wv, lane, m0, (kt + 1) * 64, 64);   // A-hi(kt+1)
    LGKM0();
    BARR();

    // ---- R1: MFMA Q0 [ArLo x Blo] | read B-hi | stage B-lo(kt+2) ----
#pragma unroll
    for (int m = 0; m < 4; ++m)
#pragma unroll
      for (int n = 0; n < 2; ++n) {
        acc[m][n] = MFMA_BF16(ArLo[m][0], Blo[n][0], acc[m][n], 0, 0, 0);
        acc[m][n] = MFMA_BF16(ArLo[m][1], Blo[n][1], acc[m][n], 0, 0, 0);
      }
#pragma unroll
    for (int n = 0; n < 2; ++n) {
      Bhi[n][0] = frg(lb, rB + (n + 2) * 16, cx0);
      Bhi[n][1] = frg(lb, rB + (n + 2) * 16, cx1);
    }
    if (st2) stage_b64(B, bC, wv, lane, n0, (kt + 2) * 64, 0);    // B-lo(kt+2)
    LGKM0();
    BARR();

    // ---- R2: MFMA Q1 [ArLo x Bhi] | read A-hi | stage A-lo(kt+2) ----
#pragma unroll
    for (int m = 0; m < 4; ++m)
#pragma unroll
      for (int n = 0; n < 2; ++n) {
        acc[m][n + 2] = MFMA_BF16(ArLo[m][0], Bhi[n][0], acc[m][n + 2], 0, 0, 0);
        acc[m][n + 2] = MFMA_BF16(ArLo[m][1], Bhi[n][1], acc[m][n + 2], 0, 0, 0);
      }
#pragma unroll
    for (int m = 0; m < 4; ++m) {
      ArHi[m][0] = frg(la, rA + (m + 4) * 16, cx0);
      ArHi[m][1] = frg(la, rA + (m + 4) * 16, cx1);
    }
    if (st2) stage_a64(A, aC, wv, lane, m0, (kt + 2) * 64, 0);    // A-lo(kt+2)
    LGKM0();
    BARR();

    // ---- R3: MFMA Q2 [ArHi x Bhi] | stage B-hi(kt+2) | vmcnt | BARR ----
#pragma unroll
    for (int m = 0; m < 4; ++m)
#pragma unroll
      for (int n = 0; n < 2; ++n) {
        acc[m + 4][n + 2] = MFMA_BF16(ArHi[m][0], Bhi[n][0], acc[m + 4][n + 2], 0, 0, 0);
        acc[m + 4][n + 2] = MFMA_BF16(ArHi[m][1], Bhi[n][1], acc[m + 4][n + 2], 0, 0, 0);
      }
    if (st2) stage_b64(B, bC, wv, lane, n0, (kt + 2) * 64, 32);   // B-hi(kt+2)
    if (st2)      asm volatile("s_waitcnt vmcnt(6)" ::: "memory");  // tile kt+1 ready
    else if (st1) asm volatile("s_waitcnt vmcnt(0)" ::: "memory");  // drain for last tile
    BARR();
  }

  // peeled final quadrant: Q3(19) from registers
#pragma unroll
  for (int m = 0; m < 4; ++m)
#pragma unroll
    for (int n = 0; n < 2; ++n) {
      acc[m + 4][n] = MFMA_BF16(ArHi[m][0], Blo[n][0], acc[m + 4][n], 0, 0, 0);
      acc[m + 4][n] = MFMA_BF16(ArHi[m][1], Blo[n][1], acc[m + 4][n], 0, 0, 0);
    }

  // ---------------- epilogue ----------------
  if (MODE == 0) {
    if (blockIdx.y >= 10) {
      // V region -> transposed vimg via per-wave LDS transpose (coalesced).
      unsigned short* scr = (wv < 4) ? (&lsA[0][0] + wv * 8192)
                                     : (&lsB[0][0] + (wv - 4) * 8192);
      const int base_c = n0 - 2 * DIM + wc * 64;
      // write phase: acc -> scratch [cloc(64)][rloc(128)], XOR-swizzled rows
#pragma unroll
      for (int n = 0; n < 4; ++n) {
        const int cloc = n * 16 + l15;
        const float bn = bias[2 * DIM + base_c + cloc];
        const int swz = (cloc & 7) << 4;
#pragma unroll
        for (int m = 0; m < 8; ++m) {
          const int rloc = m * 16 + q4 * 4;
          ushort4 w;
          w.x = f2b(acc[m][n][0] + bn);
          w.y = f2b(acc[m][n][1] + bn);
          w.z = f2b(acc[m][n][2] + bn);
          w.w = f2b(acc[m][n][3] + bn);
          *reinterpret_cast<ushort4*>(scr + cloc * 128 + (rloc ^ swz)) = w;
        }
      }
      // read phase: 16-lane groups store full 128B d-row runs
#pragma unroll
      for (int jtc = 0; jtc < 2; ++jtc) {
        const int rowg = m0 + wr * 128 + jtc * 64;
        const int chn = rowg >> 10, jtn = (rowg >> 6) & 15;
#pragma unroll
        for (int cb = 0; cb < 16; ++cb) {
          const int col = cb * 4 + q4;
          const int c = base_c + col;
          const int h = c / 80;
          const int d = c - h * 80;
          const int rloc = jtc * 64 + l15 * 4;
          const ushort4 w = *reinterpret_cast<const ushort4*>(
              scr + col * 128 + (rloc ^ ((col & 7) << 4)));
          *reinterpret_cast<ushort4*>(
              vo + (size_t)((chn * 16 + h) * 16 + jtn) * VT_SH + d * 72 + l15 * 4) = w;
        }
      }
      return;
    }
    unsigned short* os;
    int nloc = n0;
    if (blockIdx.y < 5) { os = qo; }
    else                { os = ko; nloc = n0 - DIM; }
#pragma unroll
    for (int n = 0; n < 4; ++n) {
      const int cg = wc * 64 + n * 16 + l15;
      const float bn = bias[n0 + cg];
#pragma unroll
      for (int m = 0; m < 8; ++m) {
#pragma unroll
        for (int r = 0; r < 4; ++r) {
          const int row = m0 + wr * 128 + m * 16 + q4 * 4 + r;
          os[(size_t)row * DIM + nloc + cg] = f2b(acc[m][n][r] + bn);
        }
      }
    }
    return;
  }
  // MODE 1: fp32 output
#pragma unroll
  for (int n = 0; n < 4; ++n) {
    const int cg = wc * 64 + n * 16 + l15;
    const float bn = bias[n0 + cg];
#pragma unroll
    for (int m = 0; m < 8; ++m) {
#pragma unroll
      for (int r = 0; r < 4; ++r) {
        const int row = m0 + wr * 128 + m * 16 + q4 * 4 + r;
        fo[(size_t)row * DIM + n0 + cg] = acc[m][n][r] + bn;
      }
    }
  }
}

// ---------------- prepass: RoPE K -> K image (vectorized; Q is roped in attn) ----------------
__global__ void prep_k(const unsigned short* __restrict__ kbuf,
                       const float* __restrict__ cp, const float* __restrict__ sp,
                       unsigned short* __restrict__ kimg) {
  const int m = blockIdx.x, tid = threadIdx.x;
  const int ch = m >> 10, rl = m & 1023;
  const int jt = rl >> 6, rr = rl & 63;

  if (tid < 160) {
    const int h = tid / 10, j = tid - h * 10;
    const int d0 = 4 * j;
    const float4 c4 = *reinterpret_cast<const float4*>(cp + (size_t)m * HD + d0);
    const float4 s4 = *reinterpret_cast<const float4*>(sp + (size_t)m * HD + d0);
    const ushort4 lo = *reinterpret_cast<const ushort4*>(kbuf + (size_t)m * DIM + h * HD + d0);
    const ushort4 hi = *reinterpret_cast<const ushort4*>(kbuf + (size_t)m * DIM + h * HD + d0 + 40);
    ushort4 o1, o2;
    o1.x = f2b(b2f(lo.x) * c4.x - b2f(hi.x) * s4.x);
    o1.y = f2b(b2f(lo.y) * c4.y - b2f(hi.y) * s4.y);
    o1.z = f2b(b2f(lo.z) * c4.z - b2f(hi.z) * s4.z);
    o1.w = f2b(b2f(lo.w) * c4.w - b2f(hi.w) * s4.w);
    o2.x = f2b(b2f(hi.x) * c4.x + b2f(lo.x) * s4.x);
    o2.y = f2b(b2f(hi.y) * c4.y + b2f(lo.y) * s4.y);
    o2.z = f2b(b2f(hi.z) * c4.z + b2f(lo.z) * s4.z);
    o2.w = f2b(b2f(hi.w) * c4.w + b2f(lo.w) * s4.w);
    const size_t ob = ((size_t)((ch * 16 + h) * 16 + jt) * KT_SH) + rr * 104;
    *reinterpret_cast<ushort4*>(kimg + ob + d0) = o1;
    *reinterpret_cast<ushort4*>(kimg + ob + d0 + 40) = o2;
  } else {
    const int t = tid - 160;            // 0..95: 16 heads x 6 ushort4 pads
    const int h = t / 6, qi = t - h * 6;
    const size_t ob = ((size_t)((ch * 16 + h) * 16 + jt) * KT_SH) + rr * 104;
    *reinterpret_cast<ushort4*>(kimg + ob + 80 + 4 * qi) = (ushort4){0, 0, 0, 0};
  }
}

// ---------------- flash attention v3 (dbuf K/V staging; RoPE-Q on load) ----------------
// Round-10: natural block order restored (round-9's XCD grouping relied on an
// undefined bid->XCD mapping; natural order already makes the 8 qt-blocks of
// one (ch,h) consecutive = temporally adjacent).  RoPE-Q on load kept.
__launch_bounds__(256, 2)
__global__ void attn_k(const unsigned short* __restrict__ qbuf,
                       const unsigned short* __restrict__ kimg,
                       const unsigned short* __restrict__ vimg,
                       const float* __restrict__ cp, const float* __restrict__ sp,
                       unsigned short* __restrict__ ob) {
  __shared__ __attribute__((aligned(16))) unsigned short lsK[2][KT_SH];   // 2 x 13312 B
  __shared__ __attribute__((aligned(16))) unsigned short lsV[2][VT_SH];   // 2 x 11520 B
  __shared__ __attribute__((aligned(16))) unsigned short lsP[128 * 72];   // 18432 B

  const int bx = blockIdx.x;           // qt(8) x h(16) x ch(8)
  const int qt = bx & 7, h = (bx >> 3) & 15, ch = bx >> 7;
  const int tid = threadIdx.x, wv = tid >> 6, lane = tid & 63;
  const int q4 = lane >> 4, l15 = lane & 15;
  const int qrow_loc = qt * 128 + wv * 32;

  // Q fragments: RoPE + QSCALE applied on load from row-major qbuf
  bf16x8 aq[2][3];
#pragma unroll
  for (int mt = 0; mt < 2; ++mt) {
    const int m_row = ch * 1024 + qrow_loc + mt * 16 + l15;
    const unsigned short* qr = qbuf + (size_t)m_row * DIM + h * HD;
    const float* cr = cp + (size_t)m_row * HD;
    const float* sr = sp + (size_t)m_row * HD;
#pragma unroll
    for (int ks = 0; ks < 3; ++ks) {
      const int d0 = ks * 32 + q4 * 8;
      union { ushort4 u4[2]; bf16x8 v; } out;
      if (d0 < 80) {
        const bool hi = (d0 >= 40);
        const int pd = hi ? d0 - 40 : d0 + 40;
        const float sg = hi ? 1.0f : -1.0f;
        const ushort4 xa = *reinterpret_cast<const ushort4*>(qr + d0);
        const ushort4 xc = *reinterpret_cast<const ushort4*>(qr + d0 + 4);
        const ushort4 pa = *reinterpret_cast<const ushort4*>(qr + pd);
        const ushort4 pc = *reinterpret_cast<const ushort4*>(qr + pd + 4);
        const float4 c0 = *reinterpret_cast<const float4*>(cr + d0);
        const float4 c1 = *reinterpret_cast<const float4*>(cr + d0 + 4);
        const float4 s0 = *reinterpret_cast<const float4*>(sr + d0);
        const float4 s1 = *reinterpret_cast<const float4*>(sr + d0 + 4);
        ushort4 o0, o1;
        o0.x = f2b((b2f(xa.x) * c0.x + sg * b2f(pa.x) * s0.x) * QSCALE);
        o0.y = f2b((b2f(xa.y) * c0.y + sg * b2f(pa.y) * s0.y) * QSCALE);
        o0.z = f2b((b2f(xa.z) * c0.z + sg * b2f(pa.z) * s0.z) * QSCALE);
        o0.w = f2b((b2f(xa.w) * c0.w + sg * b2f(pa.w) * s0.w) * QSCALE);
        o1.x = f2b((b2f(xc.x) * c1.x + sg * b2f(pc.x) * s1.x) * QSCALE);
        o1.y = f2b((b2f(xc.y) * c1.y + sg * b2f(pc.y) * s1.y) * QSCALE);
        o1.z = f2b((b2f(xc.z) * c1.z + sg * b2f(pc.z) * s1.z) * QSCALE);
        o1.w = f2b((b2f(xc.w) * c1.w + sg * b2f(pc.w) * s1.w) * QSCALE);
        out.u4[0] = o0; out.u4[1] = o1;
      } else {
        out.u4[0] = (ushort4){0, 0, 0, 0};
        out.u4[1] = (ushort4){0, 0, 0, 0};
      }
      aq[mt][ks] = out.v;
    }
  }

  floatx4 oacc[2][5];
  float lpart[2] = {0.f, 0.f};
#pragma unroll
  for (int mt = 0; mt < 2; ++mt)
#pragma unroll
    for (int t = 0; t < 5; ++t) oacc[mt][t] = (floatx4){0.f, 0.f, 0.f, 0.f};

  const char* kbase = (const char*)(kimg + (size_t)(ch * 16 + h) * 16 * KT_SH);
  const char* vbase = (const char*)(vimg + (size_t)(ch * 16 + h) * 16 * VT_SH);

  auto stage_kv = [&](int jt, char* lk, char* lv) {
    const char* kg = kbase + (size_t)jt * (KT_SH * 2);
#pragma unroll
    for (int r = 0; r < 4; ++r) {
      const int off = (r * 4 + wv) * 1024;
      if (off < KT_SH * 2)
        llds16(kg + off + lane * 16, lk + off);
    }
    const char* vg = vbase + (size_t)jt * (VT_SH * 2);
#pragma unroll
    for (int r = 0; r < 3; ++r) {
      const int off = (r * 4 + wv) * 1024;
      if (off < VT_SH * 2) {
        if (off + 1024 <= VT_SH * 2) llds16(vg + off + lane * 16, lv + off);
        else if (lane < 16)          llds16(vg + off + lane * 16, lv + off);
      }
    }
  };

  stage_kv(0, (char*)lsK[0], (char*)lsV[0]);

  for (int jt = 0; jt < 16; ++jt) {
    const int cur = jt & 1;
    __syncthreads();   // implicit vmcnt(0): stage(jt) landed for all waves
    if (jt + 1 < 16)
      stage_kv(jt + 1, (char*)lsK[cur ^ 1], (char*)lsV[cur ^ 1]);

    const unsigned short* lk = lsK[cur];
    const unsigned short* lv = lsV[cur];

    // S^T = K Q^T : rows = keys, cols = q-rows
    floatx4 sfr[2][4];
    __builtin_amdgcn_s_setprio(1);
#pragma unroll
    for (int c = 0; c < 4; ++c) {
      const bf16x8 ak0 = *reinterpret_cast<const bf16x8*>(&lk[(c * 16 + l15) * 104 + 0  + q4 * 8]);
      const bf16x8 ak1 = *reinterpret_cast<const bf16x8*>(&lk[(c * 16 + l15) * 104 + 32 + q4 * 8]);
      const bf16x8 ak2 = *reinterpret_cast<const bf16x8*>(&lk[(c * 16 + l15) * 104 + 64 + q4 * 8]);
#pragma unroll
      for (int mt = 0; mt < 2; ++mt) {
        floatx4 s = (floatx4){0.f, 0.f, 0.f, 0.f};
        s = __builtin_amdgcn_mfma_f32_16x16x32_bf16(ak0, aq[mt][0], s, 0, 0, 0);
        s = __builtin_amdgcn_mfma_f32_16x16x32_bf16(ak1, aq[mt][1], s, 0, 0, 0);
        s = __builtin_amdgcn_mfma_f32_16x16x32_bf16(ak2, aq[mt][2], s, 0, 0, 0);
        sfr[mt][c] = s;
      }
    }
    __builtin_amdgcn_s_setprio(0);

    // softmax numerator: p = 2^s ; packed P writes (4 consecutive keys per thread)
#pragma unroll
    for (int mt = 0; mt < 2; ++mt)
#pragma unroll
      for (int c = 0; c < 4; ++c) {
        const float p0 = fexp2(sfr[mt][c][0]);
        const float p1 = fexp2(sfr[mt][c][1]);
        const float p2 = fexp2(sfr[mt][c][2]);
        const float p3 = fexp2(sfr[mt][c][3]);
        lpart[mt] += (p0 + p1) + (p2 + p3);
        ushort4 w;
        w.x = f2b(p0); w.y = f2b(p1); w.z = f2b(p2); w.w = f2b(p3);
        *reinterpret_cast<ushort4*>(&lsP[(wv * 32 + mt * 16 + l15) * 72 + c * 16 + q4 * 4]) = w;
      }

    // O += P V   (wave-local lsP region; in-wave DS ordering covers RAW)
    __builtin_amdgcn_s_setprio(1);
#pragma unroll
    for (int ks = 0; ks < 2; ++ks) {
      const bf16x8 ap0 = *reinterpret_cast<const bf16x8*>(&lsP[(wv * 32 + 0  + l15) * 72 + ks * 32 + q4 * 8]);
      const bf16x8 ap1 = *reinterpret_cast<const bf16x8*>(&lsP[(wv * 32 + 16 + l15) * 72 + ks * 32 + q4 * 8]);
#pragma unroll
      for (int t = 0; t < 5; ++t) {
        const bf16x8 bv = *reinterpret_cast<const bf16x8*>(&lv[(t * 16 + l15) * 72 + ks * 32 + q4 * 8]);
        oacc[0][t] = __builtin_amdgcn_mfma_f32_16x16x32_bf16(ap0, bv, oacc[0][t], 0, 0, 0);
        oacc[1][t] = __builtin_amdgcn_mfma_f32_16x16x32_bf16(ap1, bv, oacc[1][t], 0, 0, 0);
      }
    }
    __builtin_amdgcn_s_setprio(0);
  }

  // l per q-row (l15) summed over this thread's keys; reduce across q4 groups
#pragma unroll
  for (int mt = 0; mt < 2; ++mt) {
    lpart[mt] += __shfl_xor(lpart[mt], 16, 64);
    lpart[mt] += __shfl_xor(lpart[mt], 32, 64);
  }
  float inv[2];
  inv[0] = 1.0f / lpart[0];
  inv[1] = 1.0f / lpart[1];

  float invr[2][4];
#pragma unroll
  for (int mt = 0; mt < 2; ++mt)
#pragma unroll
    for (int r = 0; r < 4; ++r)
      invr[mt][r] = __shfl(inv[mt], q4 * 4 + r, 64);

#pragma unroll
  for (int mt = 0; mt < 2; ++mt)
#pragma unroll
    for (int t = 0; t < 5; ++t)
#pragma unroll
      for (int r = 0; r < 4; ++r) {
        const int gr = ch * CHUNK + qrow_loc + mt * 16 + q4 * 4 + r;
        const int gc = h * HD + t * 16 + l15;
        ob[(size_t)gr * DIM + gc] = f2b(oacc[mt][t][r] * invr[mt][r]);
      }
}

extern "C" void kernel_launch(void* const* d_in, const int* in_sizes, int n_in,
                              void* d_out, int out_size, void* d_ws, size_t ws_size,
                              hipStream_t stream) {
  (void)in_sizes; (void)n_in; (void)out_size; (void)ws_size;
  const float* hs    = (const float*)d_in[0];
  const float* cosp  = (const float*)d_in[1];
  const float* sinp  = (const float*)d_in[2];
  const float* qkvw  = (const float*)d_in[3];
  const float* qkvb  = (const float*)d_in[4];
  const float* projw = (const float*)d_in[5];
  const float* projb = (const float*)d_in[6];

  char* ws = (char*)d_ws;
  // fresh regions (total footprint 126,877,696 B)
  unsigned short* xb   = (unsigned short*)(ws + 0);            // 20,971,520
  unsigned short* wq   = (unsigned short*)(ws + 20971520);     //  9,830,400
  unsigned short* qbuf = (unsigned short*)(ws + 30801920);     // 20,971,520 (live through attn_k!)
  unsigned short* kbuf = (unsigned short*)(ws + 51773440);     // 20,971,520
  unsigned short* vimg = (unsigned short*)(ws + 72744960);     // 23,592,960 (written by gemm8<0>)
  unsigned short* wp   = (unsigned short*)(ws + 96337920);     //  3,276,800
  unsigned short* kimg = (unsigned short*)(ws + 99614720);     // 27,262,976 -> end 126,877,696
  // aliased regions (stream-serialized reuse of dead buffers)
  unsigned short* obuf = xb;   // over xb (dead after gemm8<0>); NOT qbuf (attn reads it)

  cvt_bf16<<<TOTAL * DIM / 4 / 256, 256, 0, stream>>>(hs, xb, TOTAL * DIM / 4);
  cvt_bf16<<<QKVN * DIM / 4 / 256, 256, 0, stream>>>(qkvw, wq, QKVN * DIM / 4);
  cvt_bf16<<<DIM * DIM / 4 / 256, 256, 0, stream>>>(projw, wp, DIM * DIM / 4);

  gemm8<0><<<dim3(TOTAL / 256, QKVN / 256), 512, 0, stream>>>(
      xb, wq, qkvb, qbuf, kbuf, vimg, nullptr);

  prep_k<<<TOTAL, 256, 0, stream>>>(kbuf, cosp, sinp, kimg);

  attn_k<<<1024, 256, 0, stream>>>(qbuf, kimg, vimg, cosp, sinp, obuf);

  gemm8<1><<<dim3(TOTAL / 256, DIM / 256), 512, 0, stream>>>(
      obuf, wp, projb, nullptr, nullptr, nullptr, (float*)d_out);
}

// Round 11
// 329.751 us; speedup vs baseline: 1.0713x; 1.0152x over previous
//
#include <hip/hip_runtime.h>
#include <stdint.h>

#define DIM 1280
#define HEADS 16
#define HD 80
#define TOTAL 8192
#define CHUNK 1024
#define QKVN 3840

typedef __attribute__((ext_vector_type(8))) __bf16 bf16x8;
typedef __attribute__((ext_vector_type(4))) float floatx4;

typedef __attribute__((address_space(1))) const uint32_t gu32;
typedef __attribute__((address_space(3))) uint32_t lu32;

__device__ __forceinline__ void llds16(const void* g, void* l) {
  __builtin_amdgcn_global_load_lds((gu32*)g, (lu32*)l, 16, 0, 0);
}

__device__ __forceinline__ unsigned short f2b(float f) {
  union { __bf16 b; unsigned short u; } x; x.b = (__bf16)f; return x.u;
}
__device__ __forceinline__ float b2f(unsigned short u) {
  union { __bf16 b; unsigned short u; } x; x.u = u; return (float)x.b;
}
__device__ __forceinline__ float fexp2(float x) {
#if __has_builtin(__builtin_amdgcn_exp2f)
  return __builtin_amdgcn_exp2f(x);
#else
  return __expf(x * 0.6931471805599453f);
#endif
}

// scale(80^-0.5) * log2(e), folded into Q on load
#define QSCALE (0.11180339887498949f * 1.44269504088896340f)

// image geometry
#define KT_SH (64 * 104)        // k tile: 64 keys x (80 + 24 pad) shorts = 13312 B
#define VT_SH (80 * 72)         // v tile: 80 d-rows x (64 keys + 8 pad) shorts = 11520 B

// ---------------- fp32 -> bf16 convert ----------------
__global__ void cvt_bf16(const float* __restrict__ src, unsigned short* __restrict__ dst, int n4) {
  int i = blockIdx.x * 256 + threadIdx.x;
  if (i >= n4) return;
  float4 v = reinterpret_cast<const float4*>(src)[i];
  ushort4 o;
  o.x = f2b(v.x); o.y = f2b(v.y); o.z = f2b(v.z); o.w = f2b(v.w);
  reinterpret_cast<ushort4*>(dst)[i] = o;
}

// ================= 256x256 single-barrier-per-phase GEMM (round-3 verified) =================
// Round-10: XCD swizzle reverted (round-9: remap streamed whole A per XCD).
// Round-4 lesson: MFMA-first region order.  Round-6/7/8: V epilogue via
// per-wave LDS transpose (full 128B-contiguous stores into vimg).

// stage A half: rows [0,64)+[128,192) (hi=0) or +64 (hi=64); 2 loads/thread
__device__ __forceinline__ void stage_a64(const unsigned short* __restrict__ G,
                                          unsigned short* ls, int wv, int lane,
                                          int row0, int kk, int hi) {
#pragma unroll
  for (int t = 0; t < 2; ++t) {
    const int stripe = t * 8 + wv;
    const int rb = ((stripe >> 3) << 7) + ((stripe & 7) << 3) + hi;
    const int r = rb + (lane >> 3);
    const int ch = (lane & 7) ^ (r & 7);
    llds16(G + (size_t)(row0 + r) * DIM + kk + (ch << 3), ls + rb * 64);
  }
}

// stage B half: rows wc*64+[0,32) for all wc (hi=0) or +32 (hi=32)
__device__ __forceinline__ void stage_b64(const unsigned short* __restrict__ G,
                                          unsigned short* ls, int wv, int lane,
                                          int row0, int kk, int hi) {
#pragma unroll
  for (int t = 0; t < 2; ++t) {
    const int stripe = t * 8 + wv;
    const int rb = ((stripe >> 2) << 6) + ((stripe & 3) << 3) + hi;
    const int r = rb + (lane >> 3);
    const int ch = (lane & 7) ^ (r & 7);
    llds16(G + (size_t)(row0 + r) * DIM + kk + (ch << 3), ls + rb * 64);
  }
}

__device__ __forceinline__ bf16x8 frg(const unsigned short* ls, int r, int cx) {
  return *reinterpret_cast<const bf16x8*>(ls + r * 64 + (cx << 3));
}

#define MFMA_BF16 __builtin_amdgcn_mfma_f32_16x16x32_bf16
#define LGKM0() asm volatile("s_waitcnt lgkmcnt(0)" ::: "memory")
#define BARR()  asm volatile("s_barrier" ::: "memory")

template<int MODE>
__launch_bounds__(512, 2)
__global__ void gemm8(const unsigned short* __restrict__ A,
                      const unsigned short* __restrict__ B,
                      const float* __restrict__ bias,
                      unsigned short* __restrict__ qo,
                      unsigned short* __restrict__ ko,
                      unsigned short* __restrict__ vo,
                      float* __restrict__ fo) {
  __shared__ __attribute__((aligned(16))) unsigned short lsA[2][256 * 64];  // 64 KiB
  __shared__ __attribute__((aligned(16))) unsigned short lsB[2][256 * 64];  // 64 KiB
  const int m0 = blockIdx.x * 256;
  const int n0 = blockIdx.y * 256;
  const int tid = threadIdx.x;
  const int wv = tid >> 6, lane = tid & 63;
  const int wr = wv >> 2, wc = wv & 3;
  const int q4 = lane >> 4, l15 = lane & 15;
  const int sx = l15 & 7;
  const int cx0 = q4 ^ sx;          // swizzled chunk slot, k-chunk q4
  const int cx1 = (4 + q4) ^ sx;    // swizzled chunk slot, k-chunk 4+q4

  // ---- prologue: 7 stages (tile 0 complete + 3/4 of tile 1) ----
  stage_a64(A, &lsA[0][0], wv, lane, m0, 0, 0);    // A-lo(0)
  stage_b64(B, &lsB[0][0], wv, lane, n0, 0, 0);    // B-lo(0)
  stage_b64(B, &lsB[0][0], wv, lane, n0, 0, 32);   // B-hi(0)
  stage_a64(A, &lsA[0][0], wv, lane, m0, 0, 64);   // A-hi(0)
  stage_b64(B, &lsB[1][0], wv, lane, n0, 64, 0);   // B-lo(1)
  stage_a64(A, &lsA[1][0], wv, lane, m0, 64, 0);   // A-lo(1)
  stage_b64(B, &lsB[1][0], wv, lane, n0, 64, 32);  // B-hi(1)

  floatx4 acc[8][4];
#pragma unroll
  for (int i = 0; i < 8; ++i)
#pragma unroll
    for (int j = 0; j < 4; ++j)
      acc[i][j] = (floatx4){0.f, 0.f, 0.f, 0.f};

  asm volatile("s_waitcnt vmcnt(6)" ::: "memory");   // tile 0 fully landed
  BARR();

  const int rA = wr * 128 + l15;
  const int rB = wc * 64 + l15;

  bf16x8 ArLo[4][2], ArHi[4][2], Blo[2][2], Bhi[2][2];

#pragma unroll 2
  for (int kt = 0; kt < 20; ++kt) {
    const unsigned short* la = &lsA[kt & 1][0];
    const unsigned short* lb = &lsB[kt & 1][0];
    unsigned short* aN = &lsA[(kt & 1) ^ 1][0];   // next buf (tile kt+1)
    unsigned short* aC = &lsA[kt & 1][0];         // current buf (tile kt+2)
    unsigned short* bC = &lsB[kt & 1][0];
    const bool st1 = (kt + 1 < 20);
    const bool st2 = (kt + 2 < 20);

    // ---- R0: MFMA Q3(kt-1) [ArHi x Blo, regs] | read A-lo,B-lo | stage A-hi(kt+1) ----
    if (kt > 0) {
#pragma unroll
      for (int m = 0; m < 4; ++m)
#pragma unroll
        for (int n = 0; n < 2; ++n) {
          acc[m + 4][n] = MFMA_BF16(ArHi[m][0], Blo[n][0], acc[m + 4][n], 0, 0, 0);
          acc[m + 4][n] = MFMA_BF16(ArHi[m][1], Blo[n][1], acc[m + 4][n], 0, 0, 0);
        }
    }
#pragma unroll
    for (int m = 0; m < 4; ++m) {
      ArLo[m][0] = frg(la, rA + m * 16, cx0);
      ArLo[m][1] = frg(la, rA + m * 16, cx1);
    }
#pragma unroll
    for (int n = 0; n < 2; ++n) {
      Blo[n][0] = frg(lb, rB + n * 16, cx0);
      Blo[n][1] = frg(lb, rB + n * 16, cx1);
    }
    if (st1) stage_a64(A, aN, wv, lane, m0, (kt + 1) * 64, 64);   // A-hi(kt+1)
    LGKM0();
    BARR();

    // ---- R1: MFMA Q0 [ArLo x Blo] | read B-hi | stage B-lo(kt+2) ----
#pragma unroll
    for (int m = 0; m < 4; ++m)
#pragma unroll
      for (int n = 0; n < 2; ++n) {
        acc[m][n] = MFMA_BF16(ArLo[m][0], Blo[n][0], acc[m][n], 0, 0, 0);
        acc[m][n] = MFMA_BF16(ArLo[m][1], Blo[n][1], acc[m][n], 0, 0, 0);
      }
#pragma unroll
    for (int n = 0; n < 2; ++n) {
      Bhi[n][0] = frg(lb, rB + (n + 2) * 16, cx0);
      Bhi[n][1] = frg(lb, rB + (n + 2) * 16, cx1);
    }
    if (st2) stage_b64(B, bC, wv, lane, n0, (kt + 2) * 64, 0);    // B-lo(kt+2)
    LGKM0();
    BARR();

    // ---- R2: MFMA Q1 [ArLo x Bhi] | read A-hi | stage A-lo(kt+2) ----
#pragma unroll
    for (int m = 0; m < 4; ++m)
#pragma unroll
      for (int n = 0; n < 2; ++n) {
        acc[m][n + 2] = MFMA_BF16(ArLo[m][0], Bhi[n][0], acc[m][n + 2], 0, 0, 0);
        acc[m][n + 2] = MFMA_BF16(ArLo[m][1], Bhi[n][1], acc[m][n + 2], 0, 0, 0);
      }
#pragma unroll
    for (int m = 0; m < 4; ++m) {
      ArHi[m][0] = frg(la, rA + (m + 4) * 16, cx0);
      ArHi[m][1] = frg(la, rA + (m + 4) * 16, cx1);
    }
    if (st2) stage_a64(A, aC, wv, lane, m0, (kt + 2) * 64, 0);    // A-lo(kt+2)
    LGKM0();
    BARR();

    // ---- R3: MFMA Q2 [ArHi x Bhi] | stage B-hi(kt+2) | vmcnt | BARR ----
#pragma unroll
    for (int m = 0; m < 4; ++m)
#pragma unroll
      for (int n = 0; n < 2; ++n) {
        acc[m + 4][n + 2] = MFMA_BF16(ArHi[m][0], Bhi[n][0], acc[m + 4][n + 2], 0, 0, 0);
        acc[m + 4][n + 2] = MFMA_BF16(ArHi[m][1], Bhi[n][1], acc[m + 4][n + 2], 0, 0, 0);
      }
    if (st2) stage_b64(B, bC, wv, lane, n0, (kt + 2) * 64, 32);   // B-hi(kt+2)
    if (st2)      asm volatile("s_waitcnt vmcnt(6)" ::: "memory");  // tile kt+1 ready
    else if (st1) asm volatile("s_waitcnt vmcnt(0)" ::: "memory");  // drain for last tile
    BARR();
  }

  // peeled final quadrant: Q3(19) from registers
#pragma unroll
  for (int m = 0; m < 4; ++m)
#pragma unroll
    for (int n = 0; n < 2; ++n) {
      acc[m + 4][n] = MFMA_BF16(ArHi[m][0], Blo[n][0], acc[m + 4][n], 0, 0, 0);
      acc[m + 4][n] = MFMA_BF16(ArHi[m][1], Blo[n][1], acc[m + 4][n], 0, 0, 0);
    }

  // ---------------- epilogue ----------------
  if (MODE == 0) {
    if (blockIdx.y >= 10) {
      // V region -> transposed vimg via per-wave LDS transpose (coalesced).
      unsigned short* scr = (wv < 4) ? (&lsA[0][0] + wv * 8192)
                                     : (&lsB[0][0] + (wv - 4) * 8192);
      const int base_c = n0 - 2 * DIM + wc * 64;
      // write phase: acc -> scratch [cloc(64)][rloc(128)], XOR-swizzled rows
#pragma unroll
      for (int n = 0; n < 4; ++n) {
        const int cloc = n * 16 + l15;
        const float bn = bias[2 * DIM + base_c + cloc];
        const int swz = (cloc & 7) << 4;
#pragma unroll
        for (int m = 0; m < 8; ++m) {
          const int rloc = m * 16 + q4 * 4;
          ushort4 w;
          w.x = f2b(acc[m][n][0] + bn);
          w.y = f2b(acc[m][n][1] + bn);
          w.z = f2b(acc[m][n][2] + bn);
          w.w = f2b(acc[m][n][3] + bn);
          *reinterpret_cast<ushort4*>(scr + cloc * 128 + (rloc ^ swz)) = w;
        }
      }
      // read phase: 16-lane groups store full 128B d-row runs
#pragma unroll
      for (int jtc = 0; jtc < 2; ++jtc) {
        const int rowg = m0 + wr * 128 + jtc * 64;
        const int chn = rowg >> 10, jtn = (rowg >> 6) & 15;
#pragma unroll
        for (int cb = 0; cb < 16; ++cb) {
          const int col = cb * 4 + q4;
          const int c = base_c + col;
          const int h = c / 80;
          const int d = c - h * 80;
          const int rloc = jtc * 64 + l15 * 4;
          const ushort4 w = *reinterpret_cast<const ushort4*>(
              scr + col * 128 + (rloc ^ ((col & 7) << 4)));
          *reinterpret_cast<ushort4*>(
              vo + (size_t)((chn * 16 + h) * 16 + jtn) * VT_SH + d * 72 + l15 * 4) = w;
        }
      }
      return;
    }
    unsigned short* os;
    int nloc = n0;
    if (blockIdx.y < 5) { os = qo; }
    else                { os = ko; nloc = n0 - DIM; }
#pragma unroll
    for (int n = 0; n < 4; ++n) {
      const int cg = wc * 64 + n * 16 + l15;
      const float bn = bias[n0 + cg];
#pragma unroll
      for (int m = 0; m < 8; ++m) {
#pragma unroll
        for (int r = 0; r < 4; ++r) {
          const int row = m0 + wr * 128 + m * 16 + q4 * 4 + r;
          os[(size_t)row * DIM + nloc + cg] = f2b(acc[m][n][r] + bn);
        }
      }
    }
    return;
  }
  // MODE 1: fp32 output
#pragma unroll
  for (int n = 0; n < 4; ++n) {
    const int cg = wc * 64 + n * 16 + l15;
    const float bn = bias[n0 + cg];
#pragma unroll
    for (int m = 0; m < 8; ++m) {
#pragma unroll
      for (int r = 0; r < 4; ++r) {
        const int row = m0 + wr * 128 + m * 16 + q4 * 4 + r;
        fo[(size_t)row * DIM + n0 + cg] = acc[m][n][r] + bn;
      }
    }
  }
}

// ---------------- prepass: RoPE K -> K image (key-permuted rows) ----------------
// Round-11: keys within each 64-key tile are stored at row rho(k) =
// 16*(2*((k>>2)&1)+(k>>5)) + 4*((k>>3)&3) + (k&3)  (bijective).  With this
// permutation, the QK^T output lands so that each lane holds EXACTLY the P
// values its PV A-fragment needs (frag[ks] = {sfr[ks][0..3], sfr[ks+2][0..3]})
// -> P never touches LDS.  Softmax sums commute over the permutation; V keeps
// natural key order so the MFMA's positional k-pairing matches slot-for-slot.
__global__ void prep_k(const unsigned short* __restrict__ kbuf,
                       const float* __restrict__ cp, const float* __restrict__ sp,
                       unsigned short* __restrict__ kimg) {
  const int m = blockIdx.x, tid = threadIdx.x;
  const int ch = m >> 10, rl = m & 1023;
  const int jt = rl >> 6, rr = rl & 63;
  const int rrp = ((((rr >> 2) & 1) * 2 + (rr >> 5)) << 4) |
                  (((rr >> 3) & 3) << 2) | (rr & 3);      // permuted row

  if (tid < 160) {
    const int h = tid / 10, j = tid - h * 10;
    const int d0 = 4 * j;
    const float4 c4 = *reinterpret_cast<const float4*>(cp + (size_t)m * HD + d0);
    const float4 s4 = *reinterpret_cast<const float4*>(sp + (size_t)m * HD + d0);
    const ushort4 lo = *reinterpret_cast<const ushort4*>(kbuf + (size_t)m * DIM + h * HD + d0);
    const ushort4 hi = *reinterpret_cast<const ushort4*>(kbuf + (size_t)m * DIM + h * HD + d0 + 40);
    ushort4 o1, o2;
    o1.x = f2b(b2f(lo.x) * c4.x - b2f(hi.x) * s4.x);
    o1.y = f2b(b2f(lo.y) * c4.y - b2f(hi.y) * s4.y);
    o1.z = f2b(b2f(lo.z) * c4.z - b2f(hi.z) * s4.z);
    o1.w = f2b(b2f(lo.w) * c4.w - b2f(hi.w) * s4.w);
    o2.x = f2b(b2f(hi.x) * c4.x + b2f(lo.x) * s4.x);
    o2.y = f2b(b2f(hi.y) * c4.y + b2f(lo.y) * s4.y);
    o2.z = f2b(b2f(hi.z) * c4.z + b2f(lo.z) * s4.z);
    o2.w = f2b(b2f(hi.w) * c4.w + b2f(lo.w) * s4.w);
    const size_t ob = ((size_t)((ch * 16 + h) * 16 + jt) * KT_SH) + rrp * 104;
    *reinterpret_cast<ushort4*>(kimg + ob + d0) = o1;
    *reinterpret_cast<ushort4*>(kimg + ob + d0 + 40) = o2;
  } else {
    const int t = tid - 160;            // 0..95: 16 heads x 6 ushort4 pads
    const int h = t / 6, qi = t - h * 6;
    const size_t ob = ((size_t)((ch * 16 + h) * 16 + jt) * KT_SH) + rrp * 104;
    *reinterpret_cast<ushort4*>(kimg + ob + 80 + 4 * qi) = (ushort4){0, 0, 0, 0};
  }
}

// ---------------- flash attention v3 (dbuf K/V; RoPE-Q on load; P in registers) ----------------
// Round-11: lsP removed (key-permuted K rows make P lane-local for PV) ->
// LDS 49.7 KB -> 3 blocks/CU, -8KB/wave/jt LDS traffic, no P RAW wait.
__launch_bounds__(256, 3)
__global__ void attn_k(const unsigned short* __restrict__ qbuf,
                       const unsigned short* __restrict__ kimg,
                       const unsigned short* __restrict__ vimg,
                       const float* __restrict__ cp, const float* __restrict__ sp,
                       unsigned short* __restrict__ ob) {
  __shared__ __attribute__((aligned(16))) unsigned short lsK[2][KT_SH];   // 2 x 13312 B
  __shared__ __attribute__((aligned(16))) unsigned short lsV[2][VT_SH];   // 2 x 11520 B

  const int bx = blockIdx.x;           // qt(8) x h(16) x ch(8)
  const int qt = bx & 7, h = (bx >> 3) & 15, ch = bx >> 7;
  const int tid = threadIdx.x, wv = tid >> 6, lane = tid & 63;
  const int q4 = lane >> 4, l15 = lane & 15;
  const int qrow_loc = qt * 128 + wv * 32;

  // Q fragments: RoPE + QSCALE applied on load from row-major qbuf
  bf16x8 aq[2][3];
#pragma unroll
  for (int mt = 0; mt < 2; ++mt) {
    const int m_row = ch * 1024 + qrow_loc + mt * 16 + l15;
    const unsigned short* qr = qbuf + (size_t)m_row * DIM + h * HD;
    const float* cr = cp + (size_t)m_row * HD;
    const float* sr = sp + (size_t)m_row * HD;
#pragma unroll
    for (int ks = 0; ks < 3; ++ks) {
      const int d0 = ks * 32 + q4 * 8;
      union { ushort4 u4[2]; bf16x8 v; } out;
      if (d0 < 80) {
        const bool hi = (d0 >= 40);
        const int pd = hi ? d0 - 40 : d0 + 40;
        const float sg = hi ? 1.0f : -1.0f;
        const ushort4 xa = *reinterpret_cast<const ushort4*>(qr + d0);
        const ushort4 xc = *reinterpret_cast<const ushort4*>(qr + d0 + 4);
        const ushort4 pa_ = *reinterpret_cast<const ushort4*>(qr + pd);
        const ushort4 pc_ = *reinterpret_cast<const ushort4*>(qr + pd + 4);
        const float4 c0 = *reinterpret_cast<const float4*>(cr + d0);
        const float4 c1 = *reinterpret_cast<const float4*>(cr + d0 + 4);
        const float4 s0 = *reinterpret_cast<const float4*>(sr + d0);
        const float4 s1 = *reinterpret_cast<const float4*>(sr + d0 + 4);
        ushort4 o0, o1;
        o0.x = f2b((b2f(xa.x) * c0.x + sg * b2f(pa_.x) * s0.x) * QSCALE);
        o0.y = f2b((b2f(xa.y) * c0.y + sg * b2f(pa_.y) * s0.y) * QSCALE);
        o0.z = f2b((b2f(xa.z) * c0.z + sg * b2f(pa_.z) * s0.z) * QSCALE);
        o0.w = f2b((b2f(xa.w) * c0.w + sg * b2f(pa_.w) * s0.w) * QSCALE);
        o1.x = f2b((b2f(xc.x) * c1.x + sg * b2f(pc_.x) * s1.x) * QSCALE);
        o1.y = f2b((b2f(xc.y) * c1.y + sg * b2f(pc_.y) * s1.y) * QSCALE);
        o1.z = f2b((b2f(xc.z) * c1.z + sg * b2f(pc_.z) * s1.z) * QSCALE);
        o1.w = f2b((b2f(xc.w) * c1.w + sg * b2f(pc_.w) * s1.w) * QSCALE);
        out.u4[0] = o0; out.u4[1] = o1;
      } else {
        out.u4[0] = (ushort4){0, 0, 0, 0};
        out.u4[1] = (ushort4){0, 0, 0, 0};
      }
      aq[mt][ks] = out.v;
    }
  }

  floatx4 oacc[2][5];
  float lpart[2] = {0.f, 0.f};
#pragma unroll
  for (int mt = 0; mt < 2; ++mt)
#pragma unroll
    for (int t = 0; t < 5; ++t) oacc[mt][t] = (floatx4){0.f, 0.f, 0.f, 0.f};

  const char* kbase = (const char*)(kimg + (size_t)(ch * 16 + h) * 16 * KT_SH);
  const char* vbase = (const char*)(vimg + (size_t)(ch * 16 + h) * 16 * VT_SH);

  auto stage_kv = [&](int jt, char* lk, char* lv) {
    const char* kg = kbase + (size_t)jt * (KT_SH * 2);
#pragma unroll
    for (int r = 0; r < 4; ++r) {
      const int off = (r * 4 + wv) * 1024;
      if (off < KT_SH * 2)
        llds16(kg + off + lane * 16, lk + off);
    }
    const char* vg = vbase + (size_t)jt * (VT_SH * 2);
#pragma unroll
    for (int r = 0; r < 3; ++r) {
      const int off = (r * 4 + wv) * 1024;
      if (off < VT_SH * 2) {
        if (off + 1024 <= VT_SH * 2) llds16(vg + off + lane * 16, lv + off);
        else if (lane < 16)          llds16(vg + off + lane * 16, lv + off);
      }
    }
  };

  stage_kv(0, (char*)lsK[0], (char*)lsV[0]);

  for (int jt = 0; jt < 16; ++jt) {
    const int cur = jt & 1;
    __syncthreads();   // implicit vmcnt(0): stage(jt) landed for all waves
    if (jt + 1 < 16)
      stage_kv(jt + 1, (char*)lsK[cur ^ 1], (char*)lsV[cur ^ 1]);

    const unsigned short* lk = lsK[cur];
    const unsigned short* lv = lsV[cur];

    // S^T = K Q^T : rows = (permuted) keys, cols = q-rows
    floatx4 sfr[2][4];
    __builtin_amdgcn_s_setprio(1);
#pragma unroll
    for (int c = 0; c < 4; ++c) {
      const bf16x8 ak0 = *reinterpret_cast<const bf16x8*>(&lk[(c * 16 + l15) * 104 + 0  + q4 * 8]);
      const bf16x8 ak1 = *reinterpret_cast<const bf16x8*>(&lk[(c * 16 + l15) * 104 + 32 + q4 * 8]);
      const bf16x8 ak2 = *reinterpret_cast<const bf16x8*>(&lk[(c * 16 + l15) * 104 + 64 + q4 * 8]);
#pragma unroll
      for (int mt = 0; mt < 2; ++mt) {
        floatx4 s = (floatx4){0.f, 0.f, 0.f, 0.f};
        s = __builtin_amdgcn_mfma_f32_16x16x32_bf16(ak0, aq[mt][0], s, 0, 0, 0);
        s = __builtin_amdgcn_mfma_f32_16x16x32_bf16(ak1, aq[mt][1], s, 0, 0, 0);
        s = __builtin_amdgcn_mfma_f32_16x16x32_bf16(ak2, aq[mt][2], s, 0, 0, 0);
        sfr[mt][c] = s;
      }
    }
    __builtin_amdgcn_s_setprio(0);

    // softmax numerator: p = 2^s ; pack P fragments IN REGISTERS.
    // Lane (q4,l15)'s sfr[c][r] = key 32*(c&1) + 8*q4 + 4*(c>>1) + r, which is
    // exactly A-frag slot j = 4*(c>>1)+r of frag[ks=c&1].
    union Pk { unsigned short u[8]; bf16x8 v; };
    Pk pa[2][2];   // [mt][ks]
#pragma unroll
    for (int mt = 0; mt < 2; ++mt)
#pragma unroll
      for (int c = 0; c < 4; ++c) {
        const float p0 = fexp2(sfr[mt][c][0]);
        const float p1 = fexp2(sfr[mt][c][1]);
        const float p2 = fexp2(sfr[mt][c][2]);
        const float p3 = fexp2(sfr[mt][c][3]);
        lpart[mt] += (p0 + p1) + (p2 + p3);
        const int ks = c & 1, jb = (c >> 1) << 2;
        pa[mt][ks].u[jb + 0] = f2b(p0);
        pa[mt][ks].u[jb + 1] = f2b(p1);
        pa[mt][ks].u[jb + 2] = f2b(p2);
        pa[mt][ks].u[jb + 3] = f2b(p3);
      }

    // O += P V   (P from registers; V natural key order)
    __builtin_amdgcn_s_setprio(1);
#pragma unroll
    for (int ks = 0; ks < 2; ++ks) {
      const bf16x8 ap0 = pa[0][ks].v;
      const bf16x8 ap1 = pa[1][ks].v;
#pragma unroll
      for (int t = 0; t < 5; ++t) {
        const bf16x8 bv = *reinterpret_cast<const bf16x8*>(&lv[(t * 16 + l15) * 72 + ks * 32 + q4 * 8]);
        oacc[0][t] = __builtin_amdgcn_mfma_f32_16x16x32_bf16(ap0, bv, oacc[0][t], 0, 0, 0);
        oacc[1][t] = __builtin_amdgcn_mfma_f32_16x16x32_bf16(ap1, bv, oacc[1][t], 0, 0, 0);
      }
    }
    __builtin_amdgcn_s_setprio(0);
  }

  // l per q-row (l15) summed over this thread's keys; reduce across q4 groups
#pragma unroll
  for (int mt = 0; mt < 2; ++mt) {
    lpart[mt] += __shfl_xor(lpart[mt], 16, 64);
    lpart[mt] += __shfl_xor(lpart[mt], 32, 64);
  }
  float inv[2];
  inv[0] = 1.0f / lpart[0];
  inv[1] = 1.0f / lpart[1];

  float invr[2][4];
#pragma unroll
  for (int mt = 0; mt < 2; ++mt)
#pragma unroll
    for (int r = 0; r < 4; ++r)
      invr[mt][r] = __shfl(inv[mt], q4 * 4 + r, 64);

#pragma unroll
  for (int mt = 0; mt < 2; ++mt)
#pragma unroll
    for (int t = 0; t < 5; ++t)
#pragma unroll
      for (int r = 0; r < 4; ++r) {
        const int gr = ch * CHUNK + qrow_loc + mt * 16 + q4 * 4 + r;
        const int gc = h * HD + t * 16 + l15;
        ob[(size_t)gr * DIM + gc] = f2b(oacc[mt][t][r] * invr[mt][r]);
      }
}

extern "C" void kernel_launch(void* const* d_in, const int* in_sizes, int n_in,
                              void* d_out, int out_size, void* d_ws, size_t ws_size,
                              hipStream_t stream) {
  (void)in_sizes; (void)n_in; (void)out_size; (void)ws_size;
  const float* hs    = (const float*)d_in[0];
  const float* cosp  = (const float*)d_in[1];
  const float* sinp  = (const float*)d_in[2];
  const float* qkvw  = (const float*)d_in[3];
  const float* qkvb  = (const float*)d_in[4];
  const float* projw = (const float*)d_in[5];
  const float* projb = (const float*)d_in[6];

  char* ws = (char*)d_ws;
  // fresh regions (total footprint 126,877,696 B)
  unsigned short* xb   = (unsigned short*)(ws + 0);            // 20,971,520
  unsigned short* wq   = (unsigned short*)(ws + 20971520);     //  9,830,400
  unsigned short* qbuf = (unsigned short*)(ws + 30801920);     // 20,971,520 (live through attn_k!)
  unsigned short* kbuf = (unsigned short*)(ws + 51773440);     // 20,971,520
  unsigned short* vimg = (unsigned short*)(ws + 72744960);     // 23,592,960 (written by gemm8<0>)
  unsigned short* wp   = (unsigned short*)(ws + 96337920);     //  3,276,800
  unsigned short* kimg = (unsigned short*)(ws + 99614720);     // 27,262,976 -> end 126,877,696
  // aliased regions (stream-serialized reuse of dead buffers)
  unsigned short* obuf = xb;   // over xb (dead after gemm8<0>); NOT qbuf (attn reads it)

  cvt_bf16<<<TOTAL * DIM / 4 / 256, 256, 0, stream>>>(hs, xb, TOTAL * DIM / 4);
  cvt_bf16<<<QKVN * DIM / 4 / 256, 256, 0, stream>>>(qkvw, wq, QKVN * DIM / 4);
  cvt_bf16<<<DIM * DIM / 4 / 256, 256, 0, stream>>>(projw, wp, DIM * DIM / 4);

  gemm8<0><<<dim3(TOTAL / 256, QKVN / 256), 512, 0, stream>>>(
      xb, wq, qkvb, qbuf, kbuf, vimg, nullptr);

  prep_k<<<TOTAL, 256, 0, stream>>>(kbuf, cosp, sinp, kimg);

  attn_k<<<1024, 256, 0, stream>>>(qbuf, kimg, vimg, cosp, sinp, obuf);

  gemm8<1><<<dim3(TOTAL / 256, DIM / 256), 512, 0, stream>>>(
      obuf, wp, projb, nullptr, nullptr, nullptr, (float*)d_out);
}